// Round 17
// baseline (227.983 us; speedup 1.0000x reference)
//
#include <hip/hip_runtime.h>

#define B_ 512
#define S_ 512
#define E_ 128
#define H_ 100
#define T_ 64
#define V_ 100000
#define BS_ (B_*S_)

typedef __attribute__((ext_vector_type(8))) short bf16x8;
typedef __attribute__((ext_vector_type(4))) float f32x4;
typedef _Float16 h2 __attribute__((ext_vector_type(2)));
union U16x4 { uint4 u; bf16x8 s; };

__device__ __forceinline__ unsigned f2bf1(float x){
    unsigned u = __float_as_uint(x);
    return (u + 0x7FFFu + ((u>>16)&1u)) >> 16;
}
__device__ __forceinline__ float bf2f(unsigned short h){
    return __uint_as_float(((unsigned)h)<<16);
}
__device__ __forceinline__ float rfl_f(float x){
    return __uint_as_float(__builtin_amdgcn_readfirstlane(__float_as_uint(x)));
}
__device__ __forceinline__ unsigned addpack3(unsigned a, unsigned b, unsigned c){
    float lo = __uint_as_float(a<<16) + __uint_as_float(b<<16) + __uint_as_float(c<<16);
    float hi = __uint_as_float(a&0xFFFF0000u) + __uint_as_float(b&0xFFFF0000u)
             + __uint_as_float(c&0xFFFF0000u);
    return f2bf1(lo) | (f2bf1(hi)<<16);
}
__device__ __forceinline__ float fdot2h(unsigned u, h2 e, float c){
    h2 p; __builtin_memcpy(&p, &u, 4);
#if __has_builtin(__builtin_amdgcn_fdot2)
    return __builtin_amdgcn_fdot2(p, e, c, false);
#else
    return fmaf((float)p.x, (float)e.x, fmaf((float)p.y, (float)e.y, c));
#endif
}
// DPP cross-lane (VALU path — NOT DS ops):
// xor1 = quad_perm[1,0,3,2]=0xB1; xor2 = quad_perm[2,3,0,1]=0x4E;
// xor7 = row_half_mirror (reverse of 3 bits == XOR 7) = 0x141
__device__ __forceinline__ float dpp_xor1(float x){
    return __int_as_float(__builtin_amdgcn_mov_dpp(__float_as_int(x), 0xB1, 0xF, 0xF, true));
}
__device__ __forceinline__ float dpp_xor2(float x){
    return __int_as_float(__builtin_amdgcn_mov_dpp(__float_as_int(x), 0x4E, 0xF, 0xF, true));
}
__device__ __forceinline__ float dpp_xor7(float x){
    return __int_as_float(__builtin_amdgcn_mov_dpp(__float_as_int(x), 0x141, 0xF, 0xF, true));
}

// ---------------------------------------------------------------------------
// prep_tbl: fp32 emb table -> bf16 copy.
// ---------------------------------------------------------------------------
__global__ __launch_bounds__(256) void prep_tbl(
    const float* __restrict__ tbl, uint2* __restrict__ tblh)
{
    int idx = blockIdx.x*256 + threadIdx.x;
    if (idx < (V_*E_)/4) {
        float4 v = ((const float4*)tbl)[idx];
        uint2 o;
        o.x = f2bf1(v.x) | (f2bf1(v.y)<<16);
        o.y = f2bf1(v.z) | (f2bf1(v.w)<<16);
        tblh[idx] = o;
    }
}

// ---------------------------------------------------------------------------
// prep_w: W1/W2 bf16 MFMA B-fragment images.
// ---------------------------------------------------------------------------
__global__ __launch_bounds__(64) void prep_w(
    const float* __restrict__ W1, const float* __restrict__ W2,
    uint4* __restrict__ W1f, uint4* __restrict__ W2f)
{
    const int idx = blockIdx.x*64 + threadIdx.x;
    if (idx < 7*4*64) {
        int lane = idx & 63, kt = (idx>>6)&3, nt = idx>>8;
        int n = nt*16 + (lane&15);
        int kb = kt*32 + (lane>>4)*8;
        unsigned wv[4];
        #pragma unroll
        for (int p = 0; p < 4; ++p) {
            float v0 = (n < H_) ? W1[(kb+2*p  )*H_ + n] : 0.f;
            float v1 = (n < H_) ? W1[(kb+2*p+1)*H_ + n] : 0.f;
            wv[p] = f2bf1(v0) | (f2bf1(v1) << 16);
        }
        W1f[idx] = make_uint4(wv[0],wv[1],wv[2],wv[3]);
    } else {
        int id2 = idx - 7*4*64;
        int lane = id2 & 63, kt = (id2>>6)&3, nt = id2>>8;
        int n = nt*16 + (lane&15);
        int kb = kt*32 + (lane>>4)*8;
        unsigned wv[4];
        #pragma unroll
        for (int p = 0; p < 4; ++p) {
            int k0 = kb+2*p, k1 = kb+2*p+1;
            float v0 = (k0 < H_) ? W2[k0*T_ + n] : 0.f;
            float v1 = (k1 < H_) ? W2[k1*T_ + n] : 0.f;
            wv[p] = f2bf1(v0) | (f2bf1(v1) << 16);
        }
        W2f[id2] = make_uint4(wv[0],wv[1],wv[2],wv[3]);
    }
}

// ---------------------------------------------------------------------------
// FUSED kernel (r16 structure). ROUND 17 changes:
//  (1) CORRECTNESS: bwd baseOf was 480-16p — rows 496..511 never produced
//      (bwd em stream shifted 4 groups; numerator missing t=496..511 and
//      double-counting t=240..255). That was the deterministic absmax=16.0.
//      Fixed: 496-16p (slot/group/numerator coverage now exact).
//  (2) PERF: 8-way split matvec — 1x ds_read_b128 (8-input slice), 8
//      output-partials (32 fdot2 in 8x4 chains), reduce-scatter via
//      row_half_mirror(xor7)+xor2+xor1 DPP. DS ops/step: 3 -> 2.
// ---------------------------------------------------------------------------
__global__ __launch_bounds__(128)
__attribute__((amdgpu_waves_per_eu(1, 1)))
void fused_kernel(
    const int* __restrict__ inputs, const int* __restrict__ tags,
    const unsigned short* __restrict__ tblh,
    const float* __restrict__ b1, const float* __restrict__ b2,
    const uint4* __restrict__ W1f, const uint4* __restrict__ W2f,
    const float* __restrict__ start_trans, const float* __restrict__ end_trans,
    const float* __restrict__ trans, float* __restrict__ out)
{
    __shared__ uint4 sW1f[1792];                         // 28 KB
    __shared__ uint4 sW2f[1024];                         // 16 KB
    __shared__ __align__(16) unsigned short ring[2][4][512];  // 8 KB
    __shared__ uint4 sA2[2][256];                        // 8 KB
    __shared__ __align__(16) _Float16 pbufH[2][T_];
    __shared__ float pubB[T_];
    __shared__ float fnum[2];
    __shared__ int   icnt[2];
    __shared__ float lsB_sh;

    const int b   = blockIdx.x;
    const int tid = threadIdx.x;
    const int w   = tid >> 6;            // 0 = fwd wave, 1 = bwd wave
    const int j   = tid & 63;
    const int col = j & 15;
    const int hi  = j >> 4;
    const int rowin = hi * 4;
    const int qm8 = j & 7;               // input slice (8 inputs)
    const int qg8 = j >> 3;              // output group (8 outputs)
    const bool qb0 = (j & 1) != 0;
    const bool qb1 = (j & 2) != 0;
    const bool qb2 = (j & 4) != 0;
    const int* tags_b = tags + b*S_;
    const int* in_b   = inputs + (size_t)b*S_*3;

    for (int i = tid; i < 1792; i += 128) sW1f[i] = W1f[i];
    for (int i = tid; i < 1024; i += 128) sW2f[i] = W2f[i];

    // ---- mask ballots for THIS wave's half ----
    unsigned long long mball[4];
    #pragma unroll
    for (int g4 = 0; g4 < 4; ++g4) {
        int t = (w*4 + g4)*64 + j;
        int a0 = in_b[t*3+0], a1 = in_b[t*3+1], a2 = in_b[t*3+2];
        mball[g4] = __ballot((a0 | a1 | a2) != 0);
    }
    int cnt = 0;
    #pragma unroll
    for (int g4 = 0; g4 < 4; ++g4) cnt += __popcll(mball[g4]);
    if (j == 0) icnt[w] = cnt;
    if (w == 0) mball[0] &= ~1ull;

    __syncthreads();

    float bv1[7], bv2[4];
    #pragma unroll
    for (int nt = 0; nt < 7; ++nt) { int n = nt*16+col; bv1[nt] = (n < H_) ? b1[n] : 0.f; }
    #pragma unroll
    for (int nt2 = 0; nt2 < 4; ++nt2) bv2[nt2] = b2[nt2*16+col];

    // E slice in fp16: 8 outputs (qg8) x 8 inputs (qm8) = 32 h2
    // fwd: y_j' = sum_i E[i][j'] x_i ;  bwd: y_j' = sum_i E[j'][i] x_i
    h2 E2[32];
    #pragma unroll
    for (int o = 0; o < 8; ++o)
        #pragma unroll
        for (int i2 = 0; i2 < 4; ++i2) {
            int r0, c0, r1, c1;
            if (w == 0) { r0 = 8*qm8 + 2*i2; c0 = 8*qg8 + o; r1 = r0 + 1; c1 = c0; }
            else        { r0 = 8*qg8 + o; c0 = 8*qm8 + 2*i2; r1 = r0; c1 = c0 + 1; }
            h2 e; e.x = (_Float16)__expf(trans[r0*T_ + c0]);
                  e.y = (_Float16)__expf(trans[r1*T_ + c1]);
            E2[o*4 + i2] = e;
        }

    // r17 FIX: bwd batches start at row 496 (not 480)
    auto baseOf = [&](int p){ return w ? (496 - 16*p) : 16*p; };
    float np = 0.f;

    auto loadIdx = [&](int p, int& x, int& y, int& z){
        int t = baseOf(p) + col;
        x = in_b[t*3 + 0]; y = in_b[t*3 + 1]; z = in_b[t*3 + 2];
    };
    auto issueGathers = [&](int i0, int i1, int i2, uint4* g){
        const unsigned short* tr0 = tblh + (size_t)i0*E_;
        const unsigned short* tr1 = tblh + (size_t)i1*E_;
        const unsigned short* tr2 = tblh + (size_t)i2*E_;
        #pragma unroll
        for (int kt = 0; kt < 4; ++kt) {
            int off = kt*32 + hi*8;
            g[kt*3+0] = *(const uint4*)(tr0 + off);
            g[kt*3+1] = *(const uint4*)(tr1 + off);
            g[kt*3+2] = *(const uint4*)(tr2 + off);
        }
    };

    auto produce = [&](int p, const uint4* g){
        U16x4 a[4];
        #pragma unroll
        for (int kt = 0; kt < 4; ++kt)
            a[kt].u = make_uint4(
                addpack3(g[kt*3+0].x, g[kt*3+1].x, g[kt*3+2].x),
                addpack3(g[kt*3+0].y, g[kt*3+1].y, g[kt*3+2].y),
                addpack3(g[kt*3+0].z, g[kt*3+1].z, g[kt*3+2].z),
                addpack3(g[kt*3+0].w, g[kt*3+1].w, g[kt*3+2].w));

        f32x4 acc1[7];
        #pragma unroll
        for (int nt = 0; nt < 7; ++nt) {
            f32x4 c; c[0]=bv1[nt]; c[1]=bv1[nt]; c[2]=bv1[nt]; c[3]=bv1[nt];
            #pragma unroll
            for (int k = 0; k < 4; ++k) {
                U16x4 bfr; bfr.u = sW1f[(nt*4+k)*64 + j];
                c = __builtin_amdgcn_mfma_f32_16x16x32_bf16(a[k].s, bfr.s, c, 0,0,0);
            }
            acc1[nt] = c;
        }
        #pragma unroll
        for (int nt = 0; nt < 7; ++nt)
            #pragma unroll
            for (int rr = 0; rr < 4; ++rr) {
                float x = acc1[nt][rr];
                acc1[nt][rr] = 1.f - 2.f/(__expf(2.f*x)+1.f);
            }

        if (j >= 32) sA2[w][3*64 + j] = make_uint4(0,0,0,0);
        unsigned short* A2h = (unsigned short*)sA2[w];
        #pragma unroll
        for (int nt = 0; nt < 7; ++nt)
            #pragma unroll
            for (int rr = 0; rr < 4; ++rr) {
                int k2 = nt*16 + col;
                int kt2 = k2 >> 5, g2 = (k2>>3)&3, i2v = k2&7;
                int u4idx = kt2*64 + g2*16 + (rowin + rr);
                A2h[u4idx*8 + i2v] = (unsigned short)f2bf1(acc1[nt][rr]);
            }
        __builtin_amdgcn_wave_barrier();

        U16x4 a2[4];
        #pragma unroll
        for (int k = 0; k < 4; ++k) a2[k].u = sA2[w][k*64 + j];
        __builtin_amdgcn_wave_barrier();

        unsigned short* tbuf = (unsigned short*)sA2[w];
        #pragma unroll
        for (int nt2 = 0; nt2 < 4; ++nt2) {
            f32x4 c; c[0]=bv2[nt2]; c[1]=bv2[nt2]; c[2]=bv2[nt2]; c[3]=bv2[nt2];
            #pragma unroll
            for (int k = 0; k < 4; ++k) {
                U16x4 bfr; bfr.u = sW2f[(nt2*4+k)*64 + j];
                c = __builtin_amdgcn_mfma_f32_16x16x32_bf16(a2[k].s, bfr.s, c, 0,0,0);
            }
            #pragma unroll
            for (int rr = 0; rr < 4; ++rr)
                tbuf[(rowin+rr)*72 + nt2*16 + col] = (unsigned short)f2bf1(c[rr]);
        }
        __builtin_amdgcn_wave_barrier();

        {
            const int rl = j >> 2;
            const int ch = (j & 3) * 2;
            const uint4* t4 = (const uint4*)tbuf;
            uint4 u0 = t4[rl*9 + ch];
            uint4 u1 = t4[rl*9 + ch + 1];
            int row = baseOf(p) + rl;
            int grp = row >> 3;
            int kidx = w ? (63 - grp) : grp;
            uint4* dst = (uint4*)&ring[w][kidx & 3][(row & 7)*64];
            dst[ch]   = u0;
            dst[ch+1] = u1;
        }
        __builtin_amdgcn_wave_barrier();

        if (j < 16) {
            int t = baseOf(p) + j;
            if (t >= 1) {
                int word = (t >> 6) - w*4;
                if ((mball[word] >> (t & 63)) & 1ull) {
                    int tp = tags_b[t-1], tc = tags_b[t];
                    int grp = t >> 3;
                    int kidx = w ? (63 - grp) : grp;
                    np += trans[tp*T_ + tc] + bf2f(ring[w][kidx & 3][(t & 7)*64 + tc]);
                }
            }
        }
    };

    // ---- prologue ----
    uint4 g[12];
    int i0, i1, i2, ni0, ni1, ni2;
    loadIdx(0, i0, i1, i2);
    issueGathers(i0, i1, i2, g);
    produce(0, g);
    float a, ls;
    if (w == 0) {
        if (j == 0) {
            int tag0 = tags_b[0];
            np += start_trans[tag0] + bf2f(ring[0][0][tag0]);
        }
        float x0v = start_trans[j] + bf2f(ring[0][0][j]);
        ls = rfl_f(x0v);
        a  = __expf(x0v - ls);
    } else {
        a  = __expf(end_trans[j]);
        ls = 0.f;
    }
    loadIdx(1, i0, i1, i2);
    issueGathers(i0, i1, i2, g);
    produce(1, g);
    loadIdx(2, i0, i1, i2);
    issueGathers(i0, i1, i2, g);
    loadIdx(3, ni0, ni1, ni2);

    float eg[8];
    #pragma unroll
    for (int s = 0; s < 8; ++s)
        eg[s] = __expf(bf2f(ring[w][0][(w ? (7-s) : s)*64 + j]));

    // ---- main loop ----
    for (int p = 0; p < 16; ++p) {
        #pragma unroll
        for (int kk = 0; kk < 2; ++kk) {
            const int k = 2*p + kk;
            unsigned short raw16[8];
            if (k < 31) {
                const unsigned short* nxt = ring[w][(k+1) & 3];
                #pragma unroll
                for (int s = 0; s < 8; ++s)
                    raw16[s] = nxt[(w ? (7-s) : s)*64 + j];
            }
            const int ag = w ? (63 - k) : k;
            const unsigned mg = (unsigned)((mball[(ag>>3) - w*4] >> ((ag&7)*8)) & 0xFFull);

            #pragma unroll
            for (int s = 0; s < 8; ++s) {
                float wv = (w == 0) ? a : (eg[s] * a);
                pbufH[w][j] = (_Float16)(wv * 0.015625f);
                __builtin_amdgcn_wave_barrier();
                float sc   = rfl_f(a);
                float sinv = __builtin_amdgcn_rcpf(sc);
                float logs = __logf(sc);
                float keep = a * sinv;
                float dmul = ((w == 0) ? (eg[s] * sinv) : sinv) * 64.0f;

                // 1x b128: this lane's 8-input slice
                const uint4* ph = (const uint4*)pbufH[w];
                uint4 U = ph[qm8];
                float pp[8];
                #pragma unroll
                for (int o = 0; o < 8; ++o) {
                    float acc = fdot2h(U.x, E2[o*4+0], 0.f);
                    acc = fdot2h(U.y, E2[o*4+1], acc);
                    acc = fdot2h(U.z, E2[o*4+2], acc);
                    acc = fdot2h(U.w, E2[o*4+3], acc);
                    pp[o] = acc;
                }
                // reduce-scatter within 8 lanes: xor7, xor2, xor1
                float k0 = qb2 ? pp[4] : pp[0], s0 = qb2 ? pp[0] : pp[4];
                float k1 = qb2 ? pp[5] : pp[1], s1 = qb2 ? pp[1] : pp[5];
                float k2v = qb2 ? pp[6] : pp[2], s2 = qb2 ? pp[2] : pp[6];
                float k3 = qb2 ? pp[7] : pp[3], s3 = qb2 ? pp[3] : pp[7];
                k0 += dpp_xor7(s0);
                k1 += dpp_xor7(s1);
                k2v += dpp_xor7(s2);
                k3 += dpp_xor7(s3);
                float m0 = qb1 ? k2v : k0, n0 = qb1 ? k0 : k2v;
                float m1 = qb1 ? k3 : k1, n1 = qb1 ? k1 : k3;
                m0 += dpp_xor2(n0);
                m1 += dpp_xor2(n1);
                float uu = qb0 ? m1 : m0, vv = qb0 ? m0 : m1;
                float y  = uu + dpp_xor1(vv);

                float cand = y * dmul;
                const int bit = (w == 0) ? s : (7 - s);
                a = ((mg >> bit) & 1u) ? cand : keep;
                ls += logs;
                __builtin_amdgcn_wave_barrier();
            }
            if (k < 31) {
                #pragma unroll
                for (int s = 0; s < 8; ++s) eg[s] = __expf(bf2f(raw16[s]));
            }
        }
        if (p <= 13) produce(p + 2, g);
        if (p <= 12) {
            issueGathers(ni0, ni1, ni2, g);
            if (p <= 11) loadIdx(p + 4, ni0, ni1, ni2);
        }
    }

    // ---- numerator reduce + merge ----
    #pragma unroll
    for (int off = 32; off >= 1; off >>= 1) np += __shfl_xor(np, off, 64);
    if (j == 0) fnum[w] = np;

    if (w == 1) {
        pubB[j] = a;
        if (j == 0) lsB_sh = ls;
    }
    __syncthreads();
    if (w == 0) {
        float x = a * pubB[j];
        #pragma unroll
        for (int off = 32; off >= 1; off >>= 1) x += __shfl_xor(x, off, 64);
        int mcount = icnt[0] + icnt[1];
        int se = mcount - 1; if (se < 0) se = 0;
        const int last_tag = tags_b[se];
        float numer = fnum[0] + fnum[1] + end_trans[last_tag];
        if (j == 0) out[b] = ls + lsB_sh + __logf(x) - numer;
    }
}

// ---------------------------------------------------------------------------
extern "C" void kernel_launch(void* const* d_in, const int* in_sizes, int n_in,
                              void* d_out, int out_size, void* d_ws, size_t ws_size,
                              hipStream_t stream) {
    const int*   inputs      = (const int*)  d_in[0];
    const int*   tags        = (const int*)  d_in[1];
    const float* emb_table   = (const float*)d_in[2];
    const float* W1          = (const float*)d_in[3];
    const float* b1          = (const float*)d_in[4];
    const float* W2          = (const float*)d_in[5];
    const float* b2          = (const float*)d_in[6];
    const float* start_trans = (const float*)d_in[7];
    const float* end_trans   = (const float*)d_in[8];
    const float* transitions = (const float*)d_in[9];
    float* out = (float*)d_out;

    // ws: tblh bf16 (25.6 MB) | W1f (28 KB) | W2f (16 KB)
    unsigned short* tblh = (unsigned short*)d_ws;
    uint4* W1f = (uint4*)((char*)d_ws + (size_t)V_*E_*2);
    uint4* W2f = W1f + 7*4*64;

    prep_tbl<<<dim3((V_*E_/4 + 255)/256), dim3(256), 0, stream>>>(emb_table, (uint2*)tblh);
    prep_w<<<dim3((7*4*64 + 4*4*64)/64), dim3(64), 0, stream>>>(W1, W2, W1f, W2f);
    fused_kernel<<<dim3(B_), dim3(128), 0, stream>>>(
        inputs, tags, tblh, b1, b2, W1f, W2f,
        start_trans, end_trans, transitions, out);
}